// Round 5
// baseline (483.310 us; speedup 1.0000x reference)
//
#include <hip/hip_runtime.h>
#include <hip/hip_bf16.h>
#include <math.h>

// Block_46643344834722: pre-norm attention block, B=512 D=2048 H=16 DH=128.
// R5: R4 + exact vmcnt accounting (always-issue refills, wrapped k when past
// end) — fixes the pipeline-tail race where vmcnt(6) was trivially satisfied
// in the last DEPTH-1 iterations and ds_read could beat global_load_lds.

#define DDIM 2048
#define HHEADS 16
#define DHEAD 128
#define BROWS 512
#define LN_EPS 1e-5f

typedef __bf16 bf16x8_t __attribute__((ext_vector_type(8)));
typedef float f32x4_t __attribute__((ext_vector_type(4)));

#define GLD16(gptr, lptr)                                                     \
    __builtin_amdgcn_global_load_lds(                                         \
        (const __attribute__((address_space(1))) void*)(gptr),                \
        (__attribute__((address_space(3))) void*)(lptr), 16, 0, 0)

// ---------------------------------------------------------------- LayerNorm
__global__ __launch_bounds__(256) void ln_kernel(const float* __restrict__ x,
                                                 const float* __restrict__ g,
                                                 const float* __restrict__ b,
                                                 __bf16* __restrict__ out) {
    const int row = blockIdx.x;
    const int tid = threadIdx.x;
    const float4* x4 = (const float4*)(x + (size_t)row * DDIM);
    float4 a = x4[2 * tid];
    float4 c = x4[2 * tid + 1];
    float s  = a.x + a.y + a.z + a.w + c.x + c.y + c.z + c.w;
    float s2 = a.x*a.x + a.y*a.y + a.z*a.z + a.w*a.w
             + c.x*c.x + c.y*c.y + c.z*c.z + c.w*c.w;
    #pragma unroll
    for (int off = 32; off > 0; off >>= 1) {
        s  += __shfl_down(s, off);
        s2 += __shfl_down(s2, off);
    }
    __shared__ float ps[4], ps2[4];
    __shared__ float mean_s, rstd_s;
    const int lane = tid & 63, w = tid >> 6;
    if (lane == 0) { ps[w] = s; ps2[w] = s2; }
    __syncthreads();
    if (tid == 0) {
        float S  = ps[0] + ps[1] + ps[2] + ps[3];
        float S2 = ps2[0] + ps2[1] + ps2[2] + ps2[3];
        float m  = S * (1.0f / DDIM);
        float var = S2 * (1.0f / DDIM) - m * m;
        mean_s = m;
        rstd_s = rsqrtf(var + LN_EPS);
    }
    __syncthreads();
    const float m = mean_s, r = rstd_s;
    const float4* g4 = (const float4*)g;
    const float4* b4 = (const float4*)b;
    float4 ga = g4[2 * tid], gb = g4[2 * tid + 1];
    float4 ba = b4[2 * tid], bb = b4[2 * tid + 1];
    bf16x8_t o;
    o[0] = (__bf16)((a.x - m) * r * ga.x + ba.x);
    o[1] = (__bf16)((a.y - m) * r * ga.y + ba.y);
    o[2] = (__bf16)((a.z - m) * r * ga.z + ba.z);
    o[3] = (__bf16)((a.w - m) * r * ga.w + ba.w);
    o[4] = (__bf16)((c.x - m) * r * gb.x + bb.x);
    o[5] = (__bf16)((c.y - m) * r * gb.y + bb.y);
    o[6] = (__bf16)((c.z - m) * r * gb.z + bb.z);
    o[7] = (__bf16)((c.w - m) * r * gb.w + bb.w);
    *(bf16x8_t*)(out + (size_t)row * DDIM + tid * 8) = o;
}

// ---------------------------------------------------------------- Transpose
__global__ __launch_bounds__(256) void transpose_kernel(
    const float* __restrict__ src, __bf16* __restrict__ dst, int R, int C) {
    __shared__ float tile[32][33];
    const size_t bofs = (size_t)blockIdx.z * R * C;
    src += bofs;
    dst += bofs;
    const int c0 = blockIdx.x * 32, r0 = blockIdx.y * 32;
    const int tx = threadIdx.x & 31, ty = threadIdx.x >> 5;  // 32 x 8
    #pragma unroll
    for (int i = 0; i < 32; i += 8)
        tile[ty + i][tx] = src[(size_t)(r0 + ty + i) * C + c0 + tx];
    __syncthreads();
    #pragma unroll
    for (int i = 0; i < 32; i += 8)
        dst[(size_t)(c0 + ty + i) * R + r0 + tx] = (__bf16)tile[tx][ty + i];
}

// ---------------------------------------------------------------- fused bias
__global__ __launch_bounds__(256) void fuse_bias_kernel(
    const float* __restrict__ bq, const float* __restrict__ bk,
    const float* __restrict__ bv, float* __restrict__ fb) {
    const int i = blockIdx.x * 256 + threadIdx.x;  // 0..6143
    float v;
    if (i < 2048) v = bq[i];
    else if (i < 4096) v = bk[i - 2048];
    else v = bv[i - 4096];
    fb[i] = v;
}

// ---------------------------------------------------------------- GEMM (B^T)
// 64x64 tile, 256 thr = 4 waves (2x2 of 32x32).  bf16 in, fp32 acc.
// Fragment-order LDS staging: chunk = 16 rows x 32 k; lane l stages
// (row l&15, k (l>>4)*8) -> LDS base + l*16 == MFMA frag order, so
// ds_read_b128 at base+lane*16 is contiguous & bank-conflict-free.
// 4-stage circular pipeline; EVERY iteration issues exactly 2 refills/wave
// (k wrapped to 0 once past the end) so vmcnt(6) always drains stage ks.
template <int OUT_BF16, int RELU, int BIAS>
__global__ __launch_bounds__(256) void gemm_bt(
    const __bf16* __restrict__ A, int lda,
    const __bf16* __restrict__ Bt, int ldb,
    int nk,                // K-steps of 32 for this split
    int kslice,            // k elems per split
    const float* __restrict__ bias,
    void* __restrict__ Cout, int N, long long zstride) {
    constexpr int DEPTH = 4;
    constexpr int STG = 4096;  // (64+64)*32 bf16 elems = 8 KB
    __shared__ __align__(16) __bf16 smem[DEPTH * STG];

    const int tid = threadIdx.x;
    const int w = tid >> 6, lane = tid & 63;
    const int m0 = blockIdx.y * 64, n0 = blockIdx.x * 64;
    const int z = blockIdx.z;

    const __bf16* Az = A + (size_t)z * kslice;
    const __bf16* Bz = Bt + (size_t)z * kslice;

    // wave w stages A-chunk w and B-chunk w (fragment order within chunk)
    const int sub_r = lane & 15;
    const int sub_k = (lane >> 4) * 8;
    const __bf16* srcA = Az + (size_t)(m0 + w * 16 + sub_r) * lda + sub_k;
    const __bf16* srcB = Bz + (size_t)(n0 + w * 16 + sub_r) * ldb + sub_k;
    const int offA = w * 512;         // bf16 elems
    const int offB = 2048 + w * 512;

    const int wm = (w >> 1) * 32, wn = (w & 1) * 32;
    const int fm = lane & 15, quad = lane >> 4;
    const int cmA = (w >> 1) * 2;     // A chunk base for this wave's frags
    const int cnB = (w & 1) * 2;

    f32x4_t acc[2][2] = {};

    // prologue: fill all DEPTH stages
    #pragma unroll
    for (int d = 0; d < DEPTH; d++) {
        GLD16(srcA + d * 32, smem + d * STG + offA);
        GLD16(srcB + d * 32, smem + d * STG + offB);
    }

    for (int ks = 0; ks < nk; ks++) {
        const __bf16* st = smem + (ks & (DEPTH - 1)) * STG;
        // queue is always 8 deep here -> this drains exactly stage ks
        asm volatile("s_waitcnt vmcnt(6)\n\ts_barrier" ::: "memory");

        bf16x8_t a[2], b[2];
        #pragma unroll
        for (int i = 0; i < 2; i++)
            a[i] = *(const bf16x8_t*)&st[(cmA + i) * 512 + lane * 8];
        #pragma unroll
        for (int j = 0; j < 2; j++)
            b[j] = *(const bf16x8_t*)&st[2048 + (cnB + j) * 512 + lane * 8];
        #pragma unroll
        for (int i = 0; i < 2; i++)
            #pragma unroll
            for (int j = 0; j < 2; j++)
                acc[i][j] = __builtin_amdgcn_mfma_f32_16x16x32_bf16(
                    a[i], b[j], acc[i][j], 0, 0, 0);

        // all waves done reading this slot before refilling it
        asm volatile("s_waitcnt lgkmcnt(0)\n\ts_barrier" ::: "memory");
        // ALWAYS refill (dummy k=0 when past end) -> exact vmcnt bookkeeping
        const int kk = (ks + DEPTH < nk) ? (ks + DEPTH) : 0;
        __bf16* dst = smem + (ks & (DEPTH - 1)) * STG;
        GLD16(srcA + kk * 32, dst + offA);
        GLD16(srcB + kk * 32, dst + offB);
    }

    // epilogue: C/D layout col=lane&15, row=quad*4+reg
    #pragma unroll
    for (int i = 0; i < 2; i++) {
        #pragma unroll
        for (int j = 0; j < 2; j++) {
            const int col = n0 + wn + j * 16 + fm;
            const float bcol = BIAS ? bias[col] : 0.0f;
            #pragma unroll
            for (int r = 0; r < 4; r++) {
                const int row = m0 + wm + i * 16 + quad * 4 + r;
                float val = acc[i][j][r] + bcol;
                if (RELU) val = fmaxf(val, 0.0f);
                if (OUT_BF16)
                    ((__bf16*)Cout)[(size_t)row * N + col] = (__bf16)val;
                else
                    ((float*)Cout)[z * zstride + (size_t)row * N + col] = val;
            }
        }
    }
}

// ---------------------------------------------------------------- split-K fuse
// out = base_in + sum_z p[z] + bias   (all fp32 [512, N=2048])
template <int SPLITS>
__global__ __launch_bounds__(256) void fuse_kernel(
    const float* __restrict__ base_in, const float* __restrict__ p,
    const float* __restrict__ bias, float* __restrict__ out) {
    const size_t i4 = (size_t)blockIdx.x * 256 + threadIdx.x;  // float4 idx
    const int col4 = i4 & (DDIM / 4 - 1);
    float4 v = ((const float4*)base_in)[i4];
    float4 bb = ((const float4*)bias)[col4];
    v.x += bb.x; v.y += bb.y; v.z += bb.z; v.w += bb.w;
    #pragma unroll
    for (int s = 0; s < SPLITS; s++) {
        float4 q = ((const float4*)p)[s * (BROWS * DDIM / 4) + i4];
        v.x += q.x; v.y += q.y; v.z += q.z; v.w += q.w;
    }
    ((float4*)out)[i4] = v;
}

// ---------------------------------------------------------------- Attention
__global__ __launch_bounds__(128) void attn_kernel(
    const __bf16* __restrict__ qkv, __bf16* __restrict__ o) {
    const int bh = blockIdx.x;  // b*H + h
    const int b = bh >> 4, h = bh & 15;
    const size_t base = (size_t)b * (3 * DDIM) + h * DHEAD;
    const int tid = threadIdx.x;
    __shared__ float ks[DHEAD], vs[DHEAD];
    ks[tid] = (float)qkv[base + DDIM + tid];
    vs[tid] = (float)qkv[base + 2 * DDIM + tid];
    __syncthreads();
    const float a = (float)qkv[base + tid] * 0.08838834764831845f;  // /sqrt(128)
    float den = 0.0f, num = 0.0f;
    #pragma unroll 8
    for (int j = 0; j < DHEAD; j++) {
        float e = __expf(a * ks[j]);
        den += e;
        num += e * vs[j];
    }
    o[(size_t)b * DDIM + h * DHEAD + tid] = (__bf16)(num / den);
}

// ---------------------------------------------------------------- launch
extern "C" void kernel_launch(void* const* d_in, const int* in_sizes, int n_in,
                              void* d_out, int out_size, void* d_ws, size_t ws_size,
                              hipStream_t stream) {
    const float* x   = (const float*)d_in[0];
    const float* Wq  = (const float*)d_in[1];
    const float* bq  = (const float*)d_in[2];
    const float* Wk  = (const float*)d_in[3];
    const float* bk  = (const float*)d_in[4];
    const float* Wv  = (const float*)d_in[5];
    const float* bv  = (const float*)d_in[6];
    const float* Wo  = (const float*)d_in[7];
    const float* bo  = (const float*)d_in[8];
    const float* W1  = (const float*)d_in[9];
    const float* b1  = (const float*)d_in[10];
    const float* W2  = (const float*)d_in[11];
    const float* b2  = (const float*)d_in[12];
    const float* g1  = (const float*)d_in[13];
    const float* be1 = (const float*)d_in[14];
    const float* g2  = (const float*)d_in[15];
    const float* be2 = (const float*)d_in[16];
    float* out = (float*)d_out;

    // ---- workspace layout ----
    char* base = (char*)d_ws;
    float*  fb     = (float*)(base);                       //   24 KB
    char*   R1     = base + 32768;                         //   32 MB
    char*   R2     = R1 + 33554432;                        //   32 MB
    char*   R3     = R2 + 33554432;                        //   14 MB
    __bf16* bt_qkv = (__bf16*)R1;                          // [6144,2048] 24 MB
    __bf16* Wot    = (__bf16*)(R1 + 25165824);             // [2048,2048]  8 MB
    __bf16* W2t    = (__bf16*)R1;                          // [2048,8192] 32 MB (late)
    __bf16* W1t    = (__bf16*)R2;                          // [8192,2048] 32 MB
    float*  w2_p   = (float*)R2;                           // 4x4 MB (late)
    float*  x1     = (float*)R3;                           // fp32 [512,2048] 4 MB
    char*   hq     = R3 + 4194304;                         // 8 MB slot
    __bf16* h      = (__bf16*)hq;                          // bf16 [512,2048]
    __bf16* qkv    = (__bf16*)(hq + 2097152);              // bf16 [512,6144]
    float*  wo_p   = (float*)hq;                           // 2x4 MB (after attn)
    __bf16* t      = (__bf16*)hq;                          // bf16 [512,8192] (late)
    char*   obslot = R3 + 12582912;                        // 2 MB slot
    __bf16* ob     = (__bf16*)obslot;                      // bf16 [512,2048]
    __bf16* h2     = (__bf16*)obslot;                      // bf16 (after wo)

    fuse_bias_kernel<<<24, 256, 0, stream>>>(bq, bk, bv, fb);

    transpose_kernel<<<dim3(4, 64, 16), 256, 0, stream>>>(Wq, bt_qkv, DDIM, DHEAD);
    transpose_kernel<<<dim3(4, 64, 16), 256, 0, stream>>>(Wk, bt_qkv + 2048 * 2048, DDIM, DHEAD);
    transpose_kernel<<<dim3(4, 64, 16), 256, 0, stream>>>(Wv, bt_qkv + 2 * 2048 * 2048, DDIM, DHEAD);
    transpose_kernel<<<dim3(64, 64, 1), 256, 0, stream>>>(Wo, Wot, DDIM, DDIM);
    transpose_kernel<<<dim3(256, 64, 1), 256, 0, stream>>>(W1, W1t, DDIM, 4 * DDIM);

    // h = LN(x)
    ln_kernel<<<BROWS, 256, 0, stream>>>(x, g1, be1, h);

    // qkv = h @ [Wq|Wk|Wv] + fb -> bf16 [512,6144]
    gemm_bt<1, 0, 1><<<dim3(96, 8), 256, 0, stream>>>(
        h, DDIM, bt_qkv, DDIM, 64, 0, fb, qkv, 3 * DDIM, 0);

    attn_kernel<<<BROWS * HHEADS, 128, 0, stream>>>(qkv, ob);

    // wo partials: ob @ Wo, split-K x2 -> fp32
    gemm_bt<0, 0, 0><<<dim3(32, 8, 2), 256, 0, stream>>>(
        ob, DDIM, Wot, DDIM, 32, 1024, nullptr, wo_p, DDIM,
        (long long)BROWS * DDIM);
    // x1 = x + sum(wo_p) + bo
    fuse_kernel<2><<<1024, 256, 0, stream>>>(x, wo_p, bo, x1);

    // h2 = LN(x1)
    ln_kernel<<<BROWS, 256, 0, stream>>>(x1, g2, be2, h2);

    // t = relu(h2 @ W1 + b1) -> bf16 [512,8192]
    gemm_bt<1, 1, 1><<<dim3(128, 8), 256, 0, stream>>>(
        h2, DDIM, W1t, DDIM, 64, 0, b1, t, 4 * DDIM, 0);

    // W2t (reuses qkv-weights region, dead after wo gemm)
    transpose_kernel<<<dim3(64, 256, 1), 256, 0, stream>>>(W2, W2t, 4 * DDIM, DDIM);

    // w2 partials: t @ W2, split-K x4 -> fp32
    gemm_bt<0, 0, 0><<<dim3(32, 8, 4), 256, 0, stream>>>(
        t, 4 * DDIM, W2t, 4 * DDIM, 64, 2048, nullptr, w2_p, DDIM,
        (long long)BROWS * DDIM);
    // out = x1 + sum(w2_p) + b2
    fuse_kernel<4><<<1024, 256, 0, stream>>>(x1, w2_p, b2, out);
}

// Round 6
// 456.092 us; speedup vs baseline: 1.0597x; 1.0597x over previous
//
#include <hip/hip_runtime.h>
#include <hip/hip_bf16.h>
#include <math.h>

// Block_46643344834722: pre-norm attention block, B=512 D=2048 H=16 DH=128.
// R6: 64x128 tiles, DEPTH=6 pipeline (72 KB LDS, 2 blocks/CU). Wave = 32x64
// output (8 MFMA/iter). Fragment-order conflict-free staging + exact vmcnt
// accounting (always-refill w/ wrapped k) carried over from R5.

#define DDIM 2048
#define HHEADS 16
#define DHEAD 128
#define BROWS 512
#define LN_EPS 1e-5f

typedef __bf16 bf16x8_t __attribute__((ext_vector_type(8)));
typedef float f32x4_t __attribute__((ext_vector_type(4)));

#define GLD16(gptr, lptr)                                                     \
    __builtin_amdgcn_global_load_lds(                                         \
        (const __attribute__((address_space(1))) void*)(gptr),                \
        (__attribute__((address_space(3))) void*)(lptr), 16, 0, 0)

// ---------------------------------------------------------------- LayerNorm
__global__ __launch_bounds__(256) void ln_kernel(const float* __restrict__ x,
                                                 const float* __restrict__ g,
                                                 const float* __restrict__ b,
                                                 __bf16* __restrict__ out) {
    const int row = blockIdx.x;
    const int tid = threadIdx.x;
    const float4* x4 = (const float4*)(x + (size_t)row * DDIM);
    float4 a = x4[2 * tid];
    float4 c = x4[2 * tid + 1];
    float s  = a.x + a.y + a.z + a.w + c.x + c.y + c.z + c.w;
    float s2 = a.x*a.x + a.y*a.y + a.z*a.z + a.w*a.w
             + c.x*c.x + c.y*c.y + c.z*c.z + c.w*c.w;
    #pragma unroll
    for (int off = 32; off > 0; off >>= 1) {
        s  += __shfl_down(s, off);
        s2 += __shfl_down(s2, off);
    }
    __shared__ float ps[4], ps2[4];
    __shared__ float mean_s, rstd_s;
    const int lane = tid & 63, w = tid >> 6;
    if (lane == 0) { ps[w] = s; ps2[w] = s2; }
    __syncthreads();
    if (tid == 0) {
        float S  = ps[0] + ps[1] + ps[2] + ps[3];
        float S2 = ps2[0] + ps2[1] + ps2[2] + ps2[3];
        float m  = S * (1.0f / DDIM);
        float var = S2 * (1.0f / DDIM) - m * m;
        mean_s = m;
        rstd_s = rsqrtf(var + LN_EPS);
    }
    __syncthreads();
    const float m = mean_s, r = rstd_s;
    const float4* g4 = (const float4*)g;
    const float4* b4 = (const float4*)b;
    float4 ga = g4[2 * tid], gb = g4[2 * tid + 1];
    float4 ba = b4[2 * tid], bb = b4[2 * tid + 1];
    bf16x8_t o;
    o[0] = (__bf16)((a.x - m) * r * ga.x + ba.x);
    o[1] = (__bf16)((a.y - m) * r * ga.y + ba.y);
    o[2] = (__bf16)((a.z - m) * r * ga.z + ba.z);
    o[3] = (__bf16)((a.w - m) * r * ga.w + ba.w);
    o[4] = (__bf16)((c.x - m) * r * gb.x + bb.x);
    o[5] = (__bf16)((c.y - m) * r * gb.y + bb.y);
    o[6] = (__bf16)((c.z - m) * r * gb.z + bb.z);
    o[7] = (__bf16)((c.w - m) * r * gb.w + bb.w);
    *(bf16x8_t*)(out + (size_t)row * DDIM + tid * 8) = o;
}

// ---------------------------------------------------------------- Transpose
__global__ __launch_bounds__(256) void transpose_kernel(
    const float* __restrict__ src, __bf16* __restrict__ dst, int R, int C) {
    __shared__ float tile[32][33];
    const size_t bofs = (size_t)blockIdx.z * R * C;
    src += bofs;
    dst += bofs;
    const int c0 = blockIdx.x * 32, r0 = blockIdx.y * 32;
    const int tx = threadIdx.x & 31, ty = threadIdx.x >> 5;  // 32 x 8
    #pragma unroll
    for (int i = 0; i < 32; i += 8)
        tile[ty + i][tx] = src[(size_t)(r0 + ty + i) * C + c0 + tx];
    __syncthreads();
    #pragma unroll
    for (int i = 0; i < 32; i += 8)
        dst[(size_t)(c0 + ty + i) * R + r0 + tx] = (__bf16)tile[tx][ty + i];
}

// ---------------------------------------------------------------- fused bias
__global__ __launch_bounds__(256) void fuse_bias_kernel(
    const float* __restrict__ bq, const float* __restrict__ bk,
    const float* __restrict__ bv, float* __restrict__ fb) {
    const int i = blockIdx.x * 256 + threadIdx.x;  // 0..6143
    float v;
    if (i < 2048) v = bq[i];
    else if (i < 4096) v = bk[i - 2048];
    else v = bv[i - 4096];
    fb[i] = v;
}

// ---------------------------------------------------------------- GEMM (B^T)
// 64x128 tile, 256 thr = 4 waves; wave computes 32x64 (2x4 MFMA 16x16x32).
// Fragment-order staging: chunk = 16 rows x 32 k (1 KB); lane l stages
// (row l&15, k (l>>4)*8) so ds_read_b128 at base+lane*16 is conflict-free.
// 12 chunks/stage (4 A + 8 B), 3 GLD per wave per stage. DEPTH=6 circular
// pipeline; EVERY iteration refills exactly 3 (k wrapped past end) so
// vmcnt(15) always drains exactly stage ks.
template <int OUT_BF16, int RELU, int BIAS>
__global__ __launch_bounds__(256) void gemm_bt(
    const __bf16* __restrict__ A, int lda,
    const __bf16* __restrict__ Bt, int ldb,
    int nk,                // K-steps of 32 for this split
    int kslice,            // k elems per split
    const float* __restrict__ bias,
    void* __restrict__ Cout, int N, long long zstride) {
    constexpr int DEPTH = 6;
    constexpr int STG = (64 + 128) * 32;  // 6144 bf16 = 12 KB
    __shared__ __align__(16) __bf16 smem[DEPTH * STG];

    const int tid = threadIdx.x;
    const int w = tid >> 6, lane = tid & 63;
    const int m0 = blockIdx.y * 64, n0 = blockIdx.x * 128;
    const int z = blockIdx.z;

    const __bf16* Az = A + (size_t)z * kslice;
    const __bf16* Bz = Bt + (size_t)z * kslice;

    const int sub_r = lane & 15;
    const int sub_k = (lane >> 4) * 8;

    // wave w stages chunk w (A rows w*16..), chunk 4+w (B rows w*16..),
    // chunk 8+w (B rows 64+w*16..) — fragment order within each chunk
    const __bf16* src0 = Az + (size_t)(m0 + w * 16 + sub_r) * lda + sub_k;
    const __bf16* src1 = Bz + (size_t)(n0 + w * 16 + sub_r) * ldb + sub_k;
    const __bf16* src2 = Bz + (size_t)(n0 + 64 + w * 16 + sub_r) * ldb + sub_k;
    const int off0 = w * 512;
    const int off1 = (4 + w) * 512;
    const int off2 = (8 + w) * 512;

    const int wm = (w >> 1) * 32, wn = (w & 1) * 64;
    const int fm = lane & 15, quad = lane >> 4;
    const int cA = (w >> 1) * 2;       // A chunk base for this wave
    const int cB = 4 + (w & 1) * 4;    // B chunk base for this wave

    f32x4_t acc[2][4] = {};

    // prologue: fill all DEPTH stages (18 loads/wave outstanding)
    #pragma unroll
    for (int d = 0; d < DEPTH; d++) {
        __bf16* st = smem + d * STG;
        GLD16(src0 + d * 32, st + off0);
        GLD16(src1 + d * 32, st + off1);
        GLD16(src2 + d * 32, st + off2);
    }

    int slot = 0;
    for (int ks = 0; ks < nk; ks++) {
        const __bf16* st = smem + slot * STG;
        // queue is always 18 deep here -> drains exactly stage ks
        asm volatile("s_waitcnt vmcnt(15)\n\ts_barrier" ::: "memory");

        bf16x8_t a[2], b[4];
        #pragma unroll
        for (int i = 0; i < 2; i++)
            a[i] = *(const bf16x8_t*)&st[(cA + i) * 512 + lane * 8];
        #pragma unroll
        for (int j = 0; j < 4; j++)
            b[j] = *(const bf16x8_t*)&st[(cB + j) * 512 + lane * 8];
        #pragma unroll
        for (int i = 0; i < 2; i++)
            #pragma unroll
            for (int j = 0; j < 4; j++)
                acc[i][j] = __builtin_amdgcn_mfma_f32_16x16x32_bf16(
                    a[i], b[j], acc[i][j], 0, 0, 0);

        // all waves done reading this slot before refilling it
        asm volatile("s_waitcnt lgkmcnt(0)\n\ts_barrier" ::: "memory");
        // ALWAYS refill 3 (dummy k=0 past end) -> exact vmcnt bookkeeping
        const int kk = (ks + DEPTH < nk) ? (ks + DEPTH) : 0;
        __bf16* dst = smem + slot * STG;
        GLD16(src0 + kk * 32, dst + off0);
        GLD16(src1 + kk * 32, dst + off1);
        GLD16(src2 + kk * 32, dst + off2);
        slot = (slot + 1 == DEPTH) ? 0 : slot + 1;
    }

    // epilogue: C/D layout col=lane&15, row=quad*4+reg
    #pragma unroll
    for (int i = 0; i < 2; i++) {
        #pragma unroll
        for (int j = 0; j < 4; j++) {
            const int col = n0 + wn + j * 16 + fm;
            const float bcol = BIAS ? bias[col] : 0.0f;
            #pragma unroll
            for (int r = 0; r < 4; r++) {
                const int row = m0 + wm + i * 16 + quad * 4 + r;
                float val = acc[i][j][r] + bcol;
                if (RELU) val = fmaxf(val, 0.0f);
                if (OUT_BF16)
                    ((__bf16*)Cout)[(size_t)row * N + col] = (__bf16)val;
                else
                    ((float*)Cout)[z * zstride + (size_t)row * N + col] = val;
            }
        }
    }
}

// ---------------------------------------------------------------- split-K fuse
// out = base_in + sum_z p[z] + bias   (all fp32 [512, N=2048])
template <int SPLITS>
__global__ __launch_bounds__(256) void fuse_kernel(
    const float* __restrict__ base_in, const float* __restrict__ p,
    const float* __restrict__ bias, float* __restrict__ out) {
    const size_t i4 = (size_t)blockIdx.x * 256 + threadIdx.x;  // float4 idx
    const int col4 = i4 & (DDIM / 4 - 1);
    float4 v = ((const float4*)base_in)[i4];
    float4 bb = ((const float4*)bias)[col4];
    v.x += bb.x; v.y += bb.y; v.z += bb.z; v.w += bb.w;
    #pragma unroll
    for (int s = 0; s < SPLITS; s++) {
        float4 q = ((const float4*)p)[s * (BROWS * DDIM / 4) + i4];
        v.x += q.x; v.y += q.y; v.z += q.z; v.w += q.w;
    }
    ((float4*)out)[i4] = v;
}

// ---------------------------------------------------------------- Attention
__global__ __launch_bounds__(128) void attn_kernel(
    const __bf16* __restrict__ qkv, __bf16* __restrict__ o) {
    const int bh = blockIdx.x;  // b*H + h
    const int b = bh >> 4, h = bh & 15;
    const size_t base = (size_t)b * (3 * DDIM) + h * DHEAD;
    const int tid = threadIdx.x;
    __shared__ float ks[DHEAD], vs[DHEAD];
    ks[tid] = (float)qkv[base + DDIM + tid];
    vs[tid] = (float)qkv[base + 2 * DDIM + tid];
    __syncthreads();
    const float a = (float)qkv[base + tid] * 0.08838834764831845f;  // /sqrt(128)
    float den = 0.0f, num = 0.0f;
    #pragma unroll 8
    for (int j = 0; j < DHEAD; j++) {
        float e = __expf(a * ks[j]);
        den += e;
        num += e * vs[j];
    }
    o[(size_t)b * DDIM + h * DHEAD + tid] = (__bf16)(num / den);
}

// ---------------------------------------------------------------- launch
extern "C" void kernel_launch(void* const* d_in, const int* in_sizes, int n_in,
                              void* d_out, int out_size, void* d_ws, size_t ws_size,
                              hipStream_t stream) {
    const float* x   = (const float*)d_in[0];
    const float* Wq  = (const float*)d_in[1];
    const float* bq  = (const float*)d_in[2];
    const float* Wk  = (const float*)d_in[3];
    const float* bk  = (const float*)d_in[4];
    const float* Wv  = (const float*)d_in[5];
    const float* bv  = (const float*)d_in[6];
    const float* Wo  = (const float*)d_in[7];
    const float* bo  = (const float*)d_in[8];
    const float* W1  = (const float*)d_in[9];
    const float* b1  = (const float*)d_in[10];
    const float* W2  = (const float*)d_in[11];
    const float* b2  = (const float*)d_in[12];
    const float* g1  = (const float*)d_in[13];
    const float* be1 = (const float*)d_in[14];
    const float* g2  = (const float*)d_in[15];
    const float* be2 = (const float*)d_in[16];
    float* out = (float*)d_out;

    // ---- workspace layout ----
    char* base = (char*)d_ws;
    float*  fb     = (float*)(base);                       //   24 KB
    char*   R1     = base + 32768;                         //   32 MB
    char*   R2     = R1 + 33554432;                        //   32 MB
    char*   R3     = R2 + 33554432;                        //   14 MB
    __bf16* bt_qkv = (__bf16*)R1;                          // [6144,2048] 24 MB
    __bf16* Wot    = (__bf16*)(R1 + 25165824);             // [2048,2048]  8 MB
    __bf16* W2t    = (__bf16*)R1;                          // [2048,8192] 32 MB (late)
    __bf16* W1t    = (__bf16*)R2;                          // [8192,2048] 32 MB
    float*  w2_p   = (float*)R2;                           // 4x4 MB (late)
    float*  x1     = (float*)R3;                           // fp32 [512,2048] 4 MB
    char*   hq     = R3 + 4194304;                         // 8 MB slot
    __bf16* h      = (__bf16*)hq;                          // bf16 [512,2048]
    __bf16* qkv    = (__bf16*)(hq + 2097152);              // bf16 [512,6144]
    float*  wo_p   = (float*)hq;                           // 2x4 MB (after attn)
    __bf16* t      = (__bf16*)hq;                          // bf16 [512,8192] (late)
    char*   obslot = R3 + 12582912;                        // 2 MB slot
    __bf16* ob     = (__bf16*)obslot;                      // bf16 [512,2048]
    __bf16* h2     = (__bf16*)obslot;                      // bf16 (after wo)

    fuse_bias_kernel<<<24, 256, 0, stream>>>(bq, bk, bv, fb);

    transpose_kernel<<<dim3(4, 64, 16), 256, 0, stream>>>(Wq, bt_qkv, DDIM, DHEAD);
    transpose_kernel<<<dim3(4, 64, 16), 256, 0, stream>>>(Wk, bt_qkv + 2048 * 2048, DDIM, DHEAD);
    transpose_kernel<<<dim3(4, 64, 16), 256, 0, stream>>>(Wv, bt_qkv + 2 * 2048 * 2048, DDIM, DHEAD);
    transpose_kernel<<<dim3(64, 64, 1), 256, 0, stream>>>(Wo, Wot, DDIM, DDIM);
    transpose_kernel<<<dim3(256, 64, 1), 256, 0, stream>>>(W1, W1t, DDIM, 4 * DDIM);

    // h = LN(x)
    ln_kernel<<<BROWS, 256, 0, stream>>>(x, g1, be1, h);

    // qkv = h @ [Wq|Wk|Wv] + fb -> bf16 [512,6144]
    gemm_bt<1, 0, 1><<<dim3(48, 8), 256, 0, stream>>>(
        h, DDIM, bt_qkv, DDIM, 64, 0, fb, qkv, 3 * DDIM, 0);

    attn_kernel<<<BROWS * HHEADS, 128, 0, stream>>>(qkv, ob);

    // wo partials: ob @ Wo, split-K x2 -> fp32
    gemm_bt<0, 0, 0><<<dim3(16, 8, 2), 256, 0, stream>>>(
        ob, DDIM, Wot, DDIM, 32, 1024, nullptr, wo_p, DDIM,
        (long long)BROWS * DDIM);
    // x1 = x + sum(wo_p) + bo
    fuse_kernel<2><<<1024, 256, 0, stream>>>(x, wo_p, bo, x1);

    // h2 = LN(x1)
    ln_kernel<<<BROWS, 256, 0, stream>>>(x1, g2, be2, h2);

    // t = relu(h2 @ W1 + b1) -> bf16 [512,8192]
    gemm_bt<1, 1, 1><<<dim3(64, 8), 256, 0, stream>>>(
        h2, DDIM, W1t, DDIM, 64, 0, b1, t, 4 * DDIM, 0);

    // W2t (reuses qkv-weights region, dead after wo gemm)
    transpose_kernel<<<dim3(64, 256, 1), 256, 0, stream>>>(W2, W2t, 4 * DDIM, DDIM);

    // w2 partials: t @ W2, split-K x4 -> fp32
    gemm_bt<0, 0, 0><<<dim3(16, 8, 4), 256, 0, stream>>>(
        t, 4 * DDIM, W2t, 4 * DDIM, 64, 2048, nullptr, w2_p, DDIM,
        (long long)BROWS * DDIM);
    // out = x1 + sum(w2_p) + b2
    fuse_kernel<4><<<1024, 256, 0, stream>>>(x1, w2_p, b2, out);
}